// Round 1
// baseline (773.516 us; speedup 1.0000x reference)
//
#include <hip/hip_runtime.h>
#include <hip/hip_bf16.h>
#include <math.h>

typedef unsigned int u32;
typedef unsigned short u16;

#define BATCH 4
#define SEQ   4096
#define DIM   768
#define HD    64
#define NROW  (BATCH*SEQ)   // 16384
#define KT    32            // k-tile for qkv gemm

__device__ __forceinline__ float bfbits2f(u16 u) {
    return __uint_as_float(((u32)u) << 16);
}
__device__ __forceinline__ u16 f2bfbits(float f) {
    return (u16)((__float_as_uint(f) + 0x8000u) >> 16);
}

// flag: 1 = inputs are bf16 bits, 0 = f32. off in elements, multiple of 4.
__device__ __forceinline__ float4 load4_dtype(const void* p, long off, int flag) {
    if (flag) {
        const u16* b = (const u16*)p + off;
        ushort4 u = *reinterpret_cast<const ushort4*>(b);
        return make_float4(bfbits2f(u.x), bfbits2f(u.y), bfbits2f(u.z), bfbits2f(u.w));
    } else {
        const float* f = (const float*)p + off;
        return *reinterpret_cast<const float4*>(f);
    }
}

// Decide whether x is packed bf16 (flag=1) or f32 (flag=0).
// For bf16 buffers the LOW half of each u32 is itself a bf16 N(0,1) sample
// (exponent ~[107..129]); for f32 buffers those bits are uniform mantissa bits.
__global__ void sniff_kernel(const u32* __restrict__ x, int* __restrict__ flag) {
    int t = threadIdx.x;  // 64 threads
    int cnt = 0;
    for (int i = 0; i < 4; ++i) {
        u32 w = x[t * 4 + i];
        u32 lo = w & 0xffffu;
        u32 e  = (lo >> 7) & 0xffu;
        if (lo == 0u || (e >= 96u && e <= 134u)) cnt++;
    }
    for (int off = 32; off > 0; off >>= 1) cnt += __shfl_down(cnt, off);
    if (t == 0) flag[0] = (cnt >= 128) ? 1 : 0;
}

// QKV projection: C[16384 x 192] = X[16384 x 768] * W^T, W rows = [Wq;Wk;Wv].
// 64-row x 192-col block tile, KT=32 k-tile, XOR-swizzled LDS (conflict <= 2-way).
__global__ __launch_bounds__(256) void qkv_kernel(
    const void* __restrict__ x,
    const void* __restrict__ wq, const void* __restrict__ wk, const void* __restrict__ wv,
    const int* __restrict__ flagp,
    float* __restrict__ qo, float* __restrict__ ko, float* __restrict__ vo)
{
    const int flag = flagp[0];
    __shared__ float Xt[KT][64];    // [k][row], col swizzled by k
    __shared__ float Wt[KT][192];   // [k][col], col swizzled by k
    const int t  = threadIdx.x;
    const int ty = t >> 4;          // rows ty*4 .. +3
    const int tx = t & 15;          // cols tx*12 .. +11
    const int row0 = blockIdx.x * 64;

    float acc[4][12];
#pragma unroll
    for (int r = 0; r < 4; ++r)
#pragma unroll
        for (int c = 0; c < 12; ++c) acc[r][c] = 0.f;

    for (int kb = 0; kb < DIM; kb += KT) {
        // stage X: 64 rows x 32 k
#pragma unroll
        for (int i = 0; i < 2; ++i) {
            int idx = i * 256 + t;        // 0..511
            int row = idx >> 3;           // 0..63
            int kq  = (idx & 7) * 4;      // 0..28
            float4 v4 = load4_dtype(x, (long)(row0 + row) * DIM + kb + kq, flag);
            int sw = ((kq >> 2) & 7) * 4;
            Xt[kq + 0][row ^ sw] = v4.x;
            Xt[kq + 1][row ^ sw] = v4.y;
            Xt[kq + 2][row ^ sw] = v4.z;
            Xt[kq + 3][row ^ sw] = v4.w;
        }
        // stage W: 192 cols x 32 k
#pragma unroll
        for (int i = 0; i < 6; ++i) {
            int idx = i * 256 + t;        // 0..1535
            int c   = idx >> 3;           // 0..191
            int kq  = (idx & 7) * 4;
            const void* wp; int cr;
            if (c < 64)       { wp = wq; cr = c; }
            else if (c < 128) { wp = wk; cr = c - 64; }
            else              { wp = wv; cr = c - 128; }
            float4 v4 = load4_dtype(wp, (long)cr * DIM + kb + kq, flag);
            int sw = ((kq >> 2) & 7) * 4;
            Wt[kq + 0][c ^ sw] = v4.x;
            Wt[kq + 1][c ^ sw] = v4.y;
            Wt[kq + 2][c ^ sw] = v4.z;
            Wt[kq + 3][c ^ sw] = v4.w;
        }
        __syncthreads();
#pragma unroll 4
        for (int kk = 0; kk < KT; ++kk) {
            int sw = ((kk >> 2) & 7) * 4;
            float4 xv = *reinterpret_cast<const float4*>(&Xt[kk][(ty * 4) ^ sw]);
            float4 w0 = *reinterpret_cast<const float4*>(&Wt[kk][(tx * 12) ^ sw]);
            float4 w1 = *reinterpret_cast<const float4*>(&Wt[kk][(tx * 12 + 4) ^ sw]);
            float4 w2 = *reinterpret_cast<const float4*>(&Wt[kk][(tx * 12 + 8) ^ sw]);
            float xr[4]  = {xv.x, xv.y, xv.z, xv.w};
            float wr[12] = {w0.x, w0.y, w0.z, w0.w, w1.x, w1.y, w1.z, w1.w,
                            w2.x, w2.y, w2.z, w2.w};
#pragma unroll
            for (int r = 0; r < 4; ++r)
#pragma unroll
                for (int c = 0; c < 12; ++c)
                    acc[r][c] += xr[r] * wr[c];
        }
        __syncthreads();
    }
#pragma unroll
    for (int r = 0; r < 4; ++r) {
        long g = row0 + ty * 4 + r;
#pragma unroll
        for (int c4 = 0; c4 < 3; ++c4) {
            int c0 = tx * 12 + c4 * 4;   // each float4 lies wholly in q, k, or v
            float4 val = make_float4(acc[r][c4*4+0], acc[r][c4*4+1],
                                     acc[r][c4*4+2], acc[r][c4*4+3]);
            if (c0 < 64)       *reinterpret_cast<float4*>(&qo[g * HD + c0])         = val;
            else if (c0 < 128) *reinterpret_cast<float4*>(&ko[g * HD + (c0 - 64)])  = val;
            else               *reinterpret_cast<float4*>(&vo[g * HD + (c0 - 128)]) = val;
        }
    }
}

// Flash attention: one block per (batch, 64-query tile), online softmax over
// 64-key tiles. Qt/Kt: [dim][pos] swizzled f32; Ss: [q][k] row-swizzled f32;
// Vs: [key][dim] bf16 bits. Total LDS 57344 B.
__global__ __launch_bounds__(256) void attn_kernel(
    const float* __restrict__ qi_, const float* __restrict__ ki_,
    const float* __restrict__ vi_, const int* __restrict__ mask,
    const int* __restrict__ flagp, void* __restrict__ out)
{
    const int flag = flagp[0];
    __shared__ float Qt[HD][64];
    __shared__ float Kt[HD][64];
    __shared__ float Ss[64][64];
    __shared__ u16   Vs[64][HD];

    const int t  = threadIdx.x;
    const int b  = blockIdx.x & 3;
    const int qt = 63 - (blockIdx.x >> 2);   // longest blocks first
    const int q0 = qt * 64;

    // load Q tile (pre-scaled by 1/sqrt(64))
#pragma unroll
    for (int i = 0; i < 4; ++i) {
        int idx = i * 256 + t;
        int qq  = idx >> 4;
        int dq  = (idx & 15) * 4;
        float4 v4 = *reinterpret_cast<const float4*>(
            &qi_[((long)(b * SEQ + q0 + qq)) * HD + dq]);
        int sw = ((dq >> 2) & 7) * 4;
        Qt[dq + 0][qq ^ sw] = v4.x * 0.125f;
        Qt[dq + 1][qq ^ sw] = v4.y * 0.125f;
        Qt[dq + 2][qq ^ sw] = v4.z * 0.125f;
        Qt[dq + 3][qq ^ sw] = v4.w * 0.125f;
    }

    const int sqr = (t >> 4) * 4;   // score-phase rows
    const int skc = (t & 15) * 4;   // score-phase cols
    const int pqi = t >> 2;         // pv-phase row
    const int phb = (t & 3) * 16;   // pv-phase h base

    float m_run = -INFINITY, l_run = 0.f;
    float oacc[16];
#pragma unroll
    for (int i = 0; i < 16; ++i) oacc[i] = 0.f;

    for (int kt = 0; kt <= qt; ++kt) {
        const int k0 = kt * 64;
        // stage K (f32 swizzled) and V (bf16)
#pragma unroll
        for (int i = 0; i < 4; ++i) {
            int idx = i * 256 + t;
            int kk_ = idx >> 4;
            int dq  = (idx & 15) * 4;
            long gk = ((long)(b * SEQ + k0 + kk_)) * HD + dq;
            float4 kv = *reinterpret_cast<const float4*>(&ki_[gk]);
            int sw = ((dq >> 2) & 7) * 4;
            Kt[dq + 0][kk_ ^ sw] = kv.x;
            Kt[dq + 1][kk_ ^ sw] = kv.y;
            Kt[dq + 2][kk_ ^ sw] = kv.z;
            Kt[dq + 3][kk_ ^ sw] = kv.w;
            float4 vv = *reinterpret_cast<const float4*>(&vi_[gk]);
            ushort4 vb;
            vb.x = f2bfbits(vv.x); vb.y = f2bfbits(vv.y);
            vb.z = f2bfbits(vv.z); vb.w = f2bfbits(vv.w);
            *reinterpret_cast<ushort4*>(&Vs[kk_][dq]) = vb;
        }
        __syncthreads();

        // scores: 4x4 micro-tile per thread
        {
            float sc[4][4];
#pragma unroll
            for (int r = 0; r < 4; ++r)
#pragma unroll
                for (int c = 0; c < 4; ++c) sc[r][c] = 0.f;
#pragma unroll 4
            for (int kk = 0; kk < HD; ++kk) {
                int sw = ((kk >> 2) & 7) * 4;
                float4 qv = *reinterpret_cast<const float4*>(&Qt[kk][sqr ^ sw]);
                float4 kv = *reinterpret_cast<const float4*>(&Kt[kk][skc ^ sw]);
                float qr_[4] = {qv.x, qv.y, qv.z, qv.w};
                float kr_[4] = {kv.x, kv.y, kv.z, kv.w};
#pragma unroll
                for (int r = 0; r < 4; ++r)
#pragma unroll
                    for (int c = 0; c < 4; ++c)
                        sc[r][c] += qr_[r] * kr_[c];
            }
#pragma unroll
            for (int r = 0; r < 4; ++r) {
                int qg  = q0 + sqr + r;
                int swS = ((sqr + r) & 7) * 4;
#pragma unroll
                for (int c = 0; c < 4; ++c) {
                    int kl = skc + c;
                    int kg = k0 + kl;
                    bool keep = (kg <= qg) && (mask[b * SEQ + kg] != 0);
                    Ss[sqr + r][kl ^ swS] = keep ? sc[r][c] : -INFINITY;
                }
            }
        }
        __syncthreads();

        // online softmax + PV: thread owns row pqi, dims phb..phb+15
        {
            int swS = (pqi & 7) * 4;
            float mt = -INFINITY;
#pragma unroll
            for (int j4 = 0; j4 < 16; ++j4) {
                float4 s4 = *reinterpret_cast<const float4*>(&Ss[pqi][(j4 * 4) ^ swS]);
                mt = fmaxf(mt, fmaxf(fmaxf(s4.x, s4.y), fmaxf(s4.z, s4.w)));
            }
            float mnew = fmaxf(m_run, mt);
            bool dead = (mnew == -INFINITY);
            float alpha = dead ? 0.f : __expf(m_run - mnew);
            m_run = mnew;
            l_run *= alpha;
#pragma unroll
            for (int i = 0; i < 16; ++i) oacc[i] *= alpha;
#pragma unroll 2
            for (int j4 = 0; j4 < 16; ++j4) {
                float4 s4 = *reinterpret_cast<const float4*>(&Ss[pqi][(j4 * 4) ^ swS]);
                float p[4];
                p[0] = dead ? 0.f : __expf(s4.x - mnew);
                p[1] = dead ? 0.f : __expf(s4.y - mnew);
                p[2] = dead ? 0.f : __expf(s4.z - mnew);
                p[3] = dead ? 0.f : __expf(s4.w - mnew);
                l_run += p[0] + p[1] + p[2] + p[3];
#pragma unroll
                for (int u = 0; u < 4; ++u) {
                    int j = j4 * 4 + u;
                    const u16* vp = &Vs[j][phb];
                    ushort4 a0 = *reinterpret_cast<const ushort4*>(vp);
                    ushort4 a1 = *reinterpret_cast<const ushort4*>(vp + 4);
                    ushort4 a2 = *reinterpret_cast<const ushort4*>(vp + 8);
                    ushort4 a3 = *reinterpret_cast<const ushort4*>(vp + 12);
                    float pv = p[u];
                    oacc[0]  += pv * bfbits2f(a0.x);
                    oacc[1]  += pv * bfbits2f(a0.y);
                    oacc[2]  += pv * bfbits2f(a0.z);
                    oacc[3]  += pv * bfbits2f(a0.w);
                    oacc[4]  += pv * bfbits2f(a1.x);
                    oacc[5]  += pv * bfbits2f(a1.y);
                    oacc[6]  += pv * bfbits2f(a1.z);
                    oacc[7]  += pv * bfbits2f(a1.w);
                    oacc[8]  += pv * bfbits2f(a2.x);
                    oacc[9]  += pv * bfbits2f(a2.y);
                    oacc[10] += pv * bfbits2f(a2.z);
                    oacc[11] += pv * bfbits2f(a2.w);
                    oacc[12] += pv * bfbits2f(a3.x);
                    oacc[13] += pv * bfbits2f(a3.y);
                    oacc[14] += pv * bfbits2f(a3.z);
                    oacc[15] += pv * bfbits2f(a3.w);
                }
            }
        }
        __syncthreads();
    }

    float rl = (l_run > 0.f) ? 1.f / l_run : 0.f;
    long g = ((long)(b * SEQ + q0 + pqi)) * HD + phb;
    if (flag) {
        __hip_bfloat16* o = (__hip_bfloat16*)out;
#pragma unroll
        for (int i = 0; i < 16; ++i) o[g + i] = __float2bfloat16(oacc[i] * rl);
    } else {
        float* o = (float*)out;
#pragma unroll
        for (int c4 = 0; c4 < 4; ++c4) {
            float4 val = make_float4(oacc[c4*4+0]*rl, oacc[c4*4+1]*rl,
                                     oacc[c4*4+2]*rl, oacc[c4*4+3]*rl);
            *reinterpret_cast<float4*>(&o[g + c4 * 4]) = val;
        }
    }
}

extern "C" void kernel_launch(void* const* d_in, const int* in_sizes, int n_in,
                              void* d_out, int out_size, void* d_ws, size_t ws_size,
                              hipStream_t stream) {
    const void* x   = d_in[0];
    const int* mask = (const int*)d_in[1];
    const void* wq  = d_in[2];
    const void* wk  = d_in[3];
    const void* wv  = d_in[4];

    char* ws  = (char*)d_ws;
    int* flag = (int*)ws;
    float* q  = (float*)(ws + 256);
    float* k  = q + (long)NROW * HD;
    float* v  = k + (long)NROW * HD;

    sniff_kernel<<<1, 64, 0, stream>>>((const u32*)x, flag);
    qkv_kernel<<<NROW / 64, 256, 0, stream>>>(x, wq, wk, wv, flag, q, k, v);
    attn_kernel<<<BATCH * (SEQ / 64), 256, 0, stream>>>(q, k, v, mask, flag, d_out);
}

// Round 3
// 199.215 us; speedup vs baseline: 3.8828x; 3.8828x over previous
//
#include <hip/hip_runtime.h>
#include <hip/hip_bf16.h>
#include <math.h>

typedef unsigned int u32;
typedef unsigned short u16;
typedef __attribute__((ext_vector_type(8))) short short8;
typedef __attribute__((ext_vector_type(4))) float f32x4;

#define BATCH 4
#define SEQ   4096
#define DIM   768
#define HD    64
#define NROW  (BATCH*SEQ)   // 16384

__device__ __forceinline__ float bfbits2f(u16 u) {
    return __uint_as_float(((u32)u) << 16);
}
__device__ __forceinline__ u16 f2bfbits(float f) {
    u32 b = __float_as_uint(f);
    return (u16)((b + 0x7fffu + ((b >> 16) & 1u)) >> 16);   // RNE
}

// ---------------- sniff: bf16-bits vs f32 inputs ----------------
__global__ void sniff_kernel(const u32* __restrict__ x, int* __restrict__ flag) {
    int t = threadIdx.x;  // 64 threads
    int cnt = 0;
    for (int i = 0; i < 4; ++i) {
        u32 w = x[t * 4 + i];
        u32 lo = w & 0xffffu;
        u32 e  = (lo >> 7) & 0xffu;
        if (lo == 0u || (e >= 96u && e <= 134u)) cnt++;
    }
    for (int off = 32; off > 0; off >>= 1) cnt += __shfl_down(cnt, off);
    if (t == 0) flag[0] = (cnt >= 128) ? 1 : 0;
}

// ---------------- prep: pack W rows into bf16 wcat[192][768] ----------------
__global__ void wprep_kernel(const void* __restrict__ wq, const void* __restrict__ wk,
                             const void* __restrict__ wv, const int* __restrict__ flagp,
                             u16* __restrict__ wcat) {
    const int n  = blockIdx.x;                 // 0..191
    const int kk = blockIdx.y * 256 + threadIdx.x;  // 0..767
    const void* src = (n < 64) ? wq : (n < 128) ? wk : wv;
    const int rr = n & 63;
    u16 outv;
    if (flagp[0]) outv = ((const u16*)src)[rr * DIM + kk];
    else          outv = f2bfbits(((const float*)src)[rr * DIM + kk]);
    wcat[n * DIM + kk] = outv;
}

// ---------------- prep: bit-pack padding mask ----------------
__global__ void maskprep_kernel(const int* __restrict__ mask, u32* __restrict__ mb) {
    int t = blockIdx.x * 64 + threadIdx.x;   // 512 words total
    u32 v = 0;
    int base = t * 32;
#pragma unroll
    for (int i = 0; i < 32; ++i)
        if (mask[base + i] != 0) v |= (1u << i);
    mb[t] = v;
}

// ---------------- QKV projection (MFMA) ----------------
// C[16384 x 192] = X[16384 x 768] * wcat^T.  Block: 32 rows x 192 cols,
// 4 waves = (strip = w&1 -> 16 rows) x (nhalf = w>>1 -> 96 cols).
// Writes q,k row-major bf16 and v transposed: vT[b][64][4096].
__global__ __launch_bounds__(256) void qkv_kernel(
    const void* __restrict__ x, const u16* __restrict__ wcat,
    const int* __restrict__ flagp,
    u16* __restrict__ qws, u16* __restrict__ kws, u16* __restrict__ vTws)
{
    const int flag = flagp[0];
    __shared__ u16 Xt[32 * 64];     // chunk-swizzled (16B chunks, chunk^=(row&7))
    __shared__ u16 Vt[32][66];      // v staging for transpose out

    const int t  = threadIdx.x;
    const int l  = t & 63;
    const int w  = t >> 6;
    const int li = l & 15;
    const int g  = l >> 4;
    const int strip = w & 1;
    const int nhalf = w >> 1;
    const int m0 = blockIdx.x * 32;
    const int b  = m0 >> 12;

    f32x4 acc[6];
#pragma unroll
    for (int i = 0; i < 6; ++i) acc[i] = (f32x4){0.f, 0.f, 0.f, 0.f};

    const int srow = t >> 3;   // staging row 0..31
    const int sc   = t & 7;    // staging 16B chunk 0..7
    const int sdst = srow * 64 + ((sc ^ (srow & 7)) * 8);

    for (int kc = 0; kc < 12; ++kc) {
        const int kk0 = kc * 64;
        // stage X tile 32x64 bf16
        if (flag) {
            const u16* xp = (const u16*)x + (long)(m0 + srow) * DIM + kk0 + sc * 8;
            *reinterpret_cast<short8*>(&Xt[sdst]) = *reinterpret_cast<const short8*>(xp);
        } else {
            const float* xp = (const float*)x + (long)(m0 + srow) * DIM + kk0 + sc * 8;
            float4 a = *reinterpret_cast<const float4*>(xp);
            float4 c = *reinterpret_cast<const float4*>(xp + 4);
            union { u16 h[8]; short8 s; } u;
            u.h[0]=f2bfbits(a.x); u.h[1]=f2bfbits(a.y); u.h[2]=f2bfbits(a.z); u.h[3]=f2bfbits(a.w);
            u.h[4]=f2bfbits(c.x); u.h[5]=f2bfbits(c.y); u.h[6]=f2bfbits(c.z); u.h[7]=f2bfbits(c.w);
            *reinterpret_cast<short8*>(&Xt[sdst]) = u.s;
        }
        __syncthreads();
        const int arow = strip * 16 + li;
        short8 af0 = *reinterpret_cast<const short8*>(&Xt[arow * 64 + ((g       ^ (arow & 7)) * 8)]);
        short8 af1 = *reinterpret_cast<const short8*>(&Xt[arow * 64 + (((4 + g) ^ (arow & 7)) * 8)]);
        __syncthreads();
#pragma unroll
        for (int ns = 0; ns < 6; ++ns) {
            const u16* wr = wcat + (long)(nhalf * 96 + ns * 16 + li) * DIM + kk0 + g * 8;
            short8 b0 = *reinterpret_cast<const short8*>(wr);
            short8 b1 = *reinterpret_cast<const short8*>(wr + 32);
            acc[ns] = __builtin_amdgcn_mfma_f32_16x16x32_bf16(af0, b0, acc[ns], 0, 0, 0);
            acc[ns] = __builtin_amdgcn_mfma_f32_16x16x32_bf16(af1, b1, acc[ns], 0, 0, 0);
        }
    }

    // epilogue: C row = m0 + strip*16 + 4g + r, col n = nhalf*96 + ns*16 + li
#pragma unroll
    for (int ns = 0; ns < 6; ++ns) {
        const int n = nhalf * 96 + ns * 16 + li;
#pragma unroll
        for (int r = 0; r < 4; ++r) {
            const int rowl = strip * 16 + 4 * g + r;
            u16 bv = f2bfbits(acc[ns][r]);
            if (n < 64)        qws[(long)(m0 + rowl) * HD + n]        = bv;
            else if (n < 128)  kws[(long)(m0 + rowl) * HD + (n - 64)] = bv;
            else               Vt[rowl][n - 128]                      = bv;
        }
    }
    __syncthreads();
    // transpose v part out: vT[(b*64+d)][ (m0&4095) + mg*8 .. +7 ]
    {
        const int d  = t >> 2;   // 0..63
        const int mg = t & 3;    // 0..3
        union { u16 h[8]; short8 s; } u;
#pragma unroll
        for (int i = 0; i < 8; ++i) u.h[i] = Vt[mg * 8 + i][d];
        u16* dst = vTws + ((long)(b * 64 + d)) * SEQ + (m0 & (SEQ - 1)) + mg * 8;
        *reinterpret_cast<short8*>(dst) = u.s;
    }
}

// ---------------- Flash attention (MFMA) ----------------
// Block: 16 queries (qt16 = 255 - bid>>2, b = bid&3). 4 waves stride the
// 64-key tiles (kt = w, w+4, ...). S computed transposed (A=K,B=Q) so each
// lane's scores all belong to q = lane&15. P C-layout -> A-layout via a
// per-wave LDS round-trip (m120-verified pattern; intra-wave RAW, no
// barrier legal/needed since waves have different trip counts).
// Block-level online-softmax merge at the end.
__global__ __launch_bounds__(256) void attn_kernel(
    const u16* __restrict__ qw, const u16* __restrict__ kw,
    const u16* __restrict__ vTw, const u32* __restrict__ maskbits,
    const int* __restrict__ flagp, void* __restrict__ out)
{
    __shared__ float Ow[4][16][64];
    __shared__ float mwS[4][16];
    __shared__ float lwS[4][16];
    __shared__ __align__(16) u16 Ps[4][16][72];  // per-wave P^T staging, padded

    const int flag = flagp[0];
    const int t  = threadIdx.x;
    const int l  = t & 63;
    const int w  = t >> 6;
    const int li = l & 15;
    const int g  = l >> 4;
    const int bid  = blockIdx.x;
    const int qt16 = 255 - (bid >> 2);
    const int b    = bid & 3;
    const int q0   = qt16 * 16;

    // Q fragments (B-operand): lane holds Q[q0+li][g*8+j (+32)]
    const u16* qrow = qw + ((long)(b * SEQ + q0 + li)) * HD + g * 8;
    short8 qf0 = *reinterpret_cast<const short8*>(qrow);
    short8 qf1 = *reinterpret_cast<const short8*>(qrow + 32);

    f32x4 O[4];
#pragma unroll
    for (int i = 0; i < 4; ++i) O[i] = (f32x4){0.f, 0.f, 0.f, 0.f};
    float m_run = -INFINITY, l_run = 0.f;

    const int nkt = ((q0 + 15) >> 6) + 1;
    const int qg  = q0 + li;
    const f32x4 z4 = (f32x4){0.f, 0.f, 0.f, 0.f};

    for (int kt = w; kt < nkt; kt += 4) {
        const int k0 = kt * 64;
        const u32 mb0 = maskbits[b * 128 + (k0 >> 5)];
        const u32 mb1 = maskbits[b * 128 + (k0 >> 5) + 1];

        // S^T tiles: A = K subtile (m=key_local=li), B = Q
        float sv[4][4];
#pragma unroll
        for (int sub = 0; sub < 4; ++sub) {
            const u16* kr = kw + ((long)(b * SEQ + k0 + sub * 16 + li)) * HD + g * 8;
            short8 kf0 = *reinterpret_cast<const short8*>(kr);
            short8 kf1 = *reinterpret_cast<const short8*>(kr + 32);
            f32x4 a = __builtin_amdgcn_mfma_f32_16x16x32_bf16(kf0, qf0, z4, 0, 0, 0);
            a = __builtin_amdgcn_mfma_f32_16x16x32_bf16(kf1, qf1, a, 0, 0, 0);
            // scale + mask: element (sub,reg) is key k0+16sub+4g+reg of query qg
            const u32 word = (sub < 2) ? mb0 : mb1;
#pragma unroll
            for (int r = 0; r < 4; ++r) {
                const int kloc = sub * 16 + 4 * g + r;
                const int kg   = k0 + kloc;
                const bool keep = (kg <= qg) && (((word >> (kloc & 31)) & 1u) != 0u);
                sv[sub][r] = keep ? a[r] * 0.125f : -INFINITY;
            }
        }
        // per-q max: per-lane over 16 + xor-reduce over the 4 lane groups
        float mt = -INFINITY;
#pragma unroll
        for (int sub = 0; sub < 4; ++sub)
#pragma unroll
            for (int r = 0; r < 4; ++r) mt = fmaxf(mt, sv[sub][r]);
        mt = fmaxf(mt, __shfl_xor(mt, 16, 64));
        mt = fmaxf(mt, __shfl_xor(mt, 32, 64));
        const float mnew = fmaxf(m_run, mt);
        const float alpha = (mnew == m_run) ? 1.f : __expf(m_run - mnew);

        float p[4][4];
        float ls = 0.f;
#pragma unroll
        for (int sub = 0; sub < 4; ++sub)
#pragma unroll
            for (int r = 0; r < 4; ++r) {
                float pv = (sv[sub][r] == -INFINITY) ? 0.f : __expf(sv[sub][r] - mnew);
                p[sub][r] = pv;
                ls += pv;
            }
        ls += __shfl_xor(ls, 16, 64);
        ls += __shfl_xor(ls, 32, 64);
        l_run = l_run * alpha + ls;
        m_run = mnew;

        // rescale O: row q' = 4g+reg needs alpha from lane 4g+reg
#pragma unroll
        for (int r = 0; r < 4; ++r) {
            const float ar = __shfl(alpha, 4 * g + r, 64);
#pragma unroll
            for (int ds = 0; ds < 4; ++ds) O[ds][r] *= ar;
        }

        // P^T (C-layout) -> A-operand layout via per-wave LDS round-trip.
        // Write: lane holds P[q=li][key = sub*16 + 4g + r]  -> Ps[w][li][key]
#pragma unroll
        for (int sub = 0; sub < 4; ++sub) {
            ushort4 st;
            st.x = f2bfbits(p[sub][0]);
            st.y = f2bfbits(p[sub][1]);
            st.z = f2bfbits(p[sub][2]);
            st.w = f2bfbits(p[sub][3]);
            *reinterpret_cast<ushort4*>(&Ps[w][li][sub * 16 + 4 * g]) = st;
        }
        // Read: A-frag lane needs P[q=li][keys g*8..+7] and [32+g*8..+7]
        short8 A1 = *reinterpret_cast<const short8*>(&Ps[w][li][g * 8]);
        short8 A2 = *reinterpret_cast<const short8*>(&Ps[w][li][32 + g * 8]);

        // PV: O[dsub] += P * V, B-frag from vT rows (16B contiguous)
#pragma unroll
        for (int ds = 0; ds < 4; ++ds) {
            const u16* vr = vTw + ((long)(b * 64 + ds * 16 + li)) * SEQ + k0 + g * 8;
            short8 vf0 = *reinterpret_cast<const short8*>(vr);
            short8 vf1 = *reinterpret_cast<const short8*>(vr + 32);
            O[ds] = __builtin_amdgcn_mfma_f32_16x16x32_bf16(A1, vf0, O[ds], 0, 0, 0);
            O[ds] = __builtin_amdgcn_mfma_f32_16x16x32_bf16(A2, vf1, O[ds], 0, 0, 0);
        }
    }

    // write per-wave partials
#pragma unroll
    for (int ds = 0; ds < 4; ++ds)
#pragma unroll
        for (int r = 0; r < 4; ++r)
            Ow[w][4 * g + r][ds * 16 + li] = O[ds][r];
    if (l < 16) { mwS[w][l] = m_run; lwS[w][l] = l_run; }
    __syncthreads();

    // combine 4 wave partials; thread -> (q = t>>4, d4 = (t&15)*4)
    {
        const int qq = t >> 4;
        const int dd = (t & 15) * 4;
        float m0v = mwS[0][qq], m1v = mwS[1][qq], m2v = mwS[2][qq], m3v = mwS[3][qq];
        float mx = fmaxf(fmaxf(m0v, m1v), fmaxf(m2v, m3v));
        float c0 = (m0v == -INFINITY) ? 0.f : __expf(m0v - mx);
        float c1 = (m1v == -INFINITY) ? 0.f : __expf(m1v - mx);
        float c2 = (m2v == -INFINITY) ? 0.f : __expf(m2v - mx);
        float c3 = (m3v == -INFINITY) ? 0.f : __expf(m3v - mx);
        float L = lwS[0][qq] * c0 + lwS[1][qq] * c1 + lwS[2][qq] * c2 + lwS[3][qq] * c3;
        float4 o0 = *reinterpret_cast<const float4*>(&Ow[0][qq][dd]);
        float4 o1 = *reinterpret_cast<const float4*>(&Ow[1][qq][dd]);
        float4 o2 = *reinterpret_cast<const float4*>(&Ow[2][qq][dd]);
        float4 o3 = *reinterpret_cast<const float4*>(&Ow[3][qq][dd]);
        float rx = c0*o0.x + c1*o1.x + c2*o2.x + c3*o3.x;
        float ry = c0*o0.y + c1*o1.y + c2*o2.y + c3*o3.y;
        float rz = c0*o0.z + c1*o1.z + c2*o2.z + c3*o3.z;
        float rw = c0*o0.w + c1*o1.w + c2*o2.w + c3*o3.w;
        const float rl = (L > 0.f) ? 1.f / L : 0.f;
        rx *= rl; ry *= rl; rz *= rl; rw *= rl;
        const long row = (long)(b * SEQ + q0 + qq);
        if (flag) {
            u16* o = (u16*)out + row * HD + dd;
            ushort4 st;
            st.x = f2bfbits(rx); st.y = f2bfbits(ry);
            st.z = f2bfbits(rz); st.w = f2bfbits(rw);
            *reinterpret_cast<ushort4*>(o) = st;
        } else {
            float* o = (float*)out + row * HD + dd;
            *reinterpret_cast<float4*>(o) = make_float4(rx, ry, rz, rw);
        }
    }
}

extern "C" void kernel_launch(void* const* d_in, const int* in_sizes, int n_in,
                              void* d_out, int out_size, void* d_ws, size_t ws_size,
                              hipStream_t stream) {
    const void* x   = d_in[0];
    const int* mask = (const int*)d_in[1];
    const void* wq  = d_in[2];
    const void* wk  = d_in[3];
    const void* wv  = d_in[4];

    char* ws   = (char*)d_ws;
    int*  flag = (int*)ws;
    u16*  q    = (u16*)(ws + 256);
    u16*  k    = q + (long)NROW * HD;
    u16*  vT   = k + (long)NROW * HD;
    u16*  wcat = vT + (long)NROW * HD;
    u32*  mb   = (u32*)(wcat + (long)192 * DIM);

    sniff_kernel<<<1, 64, 0, stream>>>((const u32*)x, flag);
    wprep_kernel<<<dim3(192, 3), 256, 0, stream>>>(wq, wk, wv, flag, wcat);
    maskprep_kernel<<<8, 64, 0, stream>>>(mask, mb);
    qkv_kernel<<<NROW / 32, 256, 0, stream>>>(x, wcat, flag, q, k, vT);
    attn_kernel<<<BATCH * 256, 256, 0, stream>>>(q, k, vT, mb, flag, d_out);
}